// Round 3
// baseline (180.294 us; speedup 1.0000x reference)
//
#include <hip/hip_runtime.h>
#include <cstdint>
#include <cstddef>

// ---------------------------------------------------------------------------
// x = mean_i( softmax(q_i K^T / 16) ) @ h   with q = h@Wq, k = h@Wk
//   = sum_j c_j h_j,  c_j = (1/N) sum_i exp(e_ij)/l_i,  l_i = sum_j exp(e_ij)
//
// Round 3:
//  pass: 2 independent MFMA chains (even/odd K), epilogue deferred one step
//        (overlaps ds_read latency, off the barrier critical path), XCD-aware
//        colchunk swizzle, launch_bounds(256,3) matching real unified-RF occ.
//  proj: coalesced W staging (float4 -> bf16 LDS), bfrag assembly via
//        conflict-free strided LDS reads; one rowtile+which per block, 2/CU.
//  finish: 128 blocks x 64 rows.
//
// ws: [0,4MB) q bf16 frag-major | [4MB,8MB) k frag-major | l fp32[8192] | c fp32[8192]
// Frag-major (32x32 A-operand layout): elem (i,d) -> tile i>>5,
//   slot (d>>4)*64 + (i&31) + 32*((d>>3)&1), byte j = d&7.
// ---------------------------------------------------------------------------

#define N_ROWS 8192
#define DIM    256

typedef __bf16 bf16x8 __attribute__((ext_vector_type(8)));
typedef unsigned short u16x8 __attribute__((ext_vector_type(8)));
typedef float f32x16 __attribute__((ext_vector_type(16)));

__device__ __forceinline__ uint16_t f2bf(float f) {
    uint32_t u = __float_as_uint(f);
    uint32_t r = (u + 0x7fffu + ((u >> 16) & 1u)) >> 16;   // RTN-even
    return (uint16_t)r;
}

// async global->LDS, 16B per lane; ldst wave-uniform base, HW adds lane*16
__device__ __forceinline__ void gld16(const void* gsrc, void* ldst) {
    __builtin_amdgcn_global_load_lds(
        (const __attribute__((address_space(1))) unsigned int*)gsrc,
        (__attribute__((address_space(3))) unsigned int*)ldst, 16, 0, 0);
}

__device__ __forceinline__ size_t frag_off(int i, int d) {
    int tile = i >> 5, il = i & 31;
    int a0 = d >> 4, hi = (d >> 3) & 1, j = d & 7;
    return (size_t)tile * 8192 + (size_t)((a0 * 64) + il + 32 * hi) * 8 + j;
}

// ---------------------------------------------------------------------------
// Kernel 1: q = (h @ Wq)/16, k = h @ Wk, bf16 frag-major. Grid 512:
// bid = rowtile*2 + which, 32 rows per block. LDS: half of W as bf16 (64KB).
// Coalesced staging + strided (conflict-free) LDS reads for B-fragments.
// Also zero-inits l_arr / c_arr / out.
// ---------------------------------------------------------------------------
__global__ __launch_bounds__(256) void proj_kernel(
        const float* __restrict__ h, const float* __restrict__ Wq,
        const float* __restrict__ Wk, uint16_t* __restrict__ qf,
        uint16_t* __restrict__ kf, float* __restrict__ l_arr,
        float* __restrict__ c_arr, float* __restrict__ out) {
    __shared__ alignas(16) uint16_t wb[256 * 128];   // 64KB: W[:, half] as bf16 row-major
    const int tid = threadIdx.x, lane = tid & 63, wave = tid >> 6;
    const int which = blockIdx.x & 1;
    const int rt = blockIdx.x >> 1;                  // 0..255 (32-row tiles)

    if (blockIdx.x < 32)       l_arr[blockIdx.x * 256 + tid] = 0.0f;
    else if (blockIdx.x < 64)  c_arr[(blockIdx.x - 32) * 256 + tid] = 0.0f;
    else if (blockIdx.x == 64) out[tid] = 0.0f;

    const float* __restrict__ W = which ? Wk : Wq;
    uint16_t* __restrict__ dst = which ? kf : qf;
    const float scale = which ? 1.0f : 0.0625f;

    // A-fragments: rows rt*32..+31, full K=256 (32x32 A layout), bf16 in regs
    bf16x8 afrag[16];
    {
        const int r = rt * 32 + (lane & 31);
        const float* hp = h + (size_t)r * DIM + ((lane >> 5) * 8);
#pragma unroll
        for (int a0 = 0; a0 < 16; a0++) {
            float4 f0 = *(const float4*)(hp + a0 * 16);
            float4 f1 = *(const float4*)(hp + a0 * 16 + 4);
            u16x8 f;
            f[0] = f2bf(f0.x); f[1] = f2bf(f0.y); f[2] = f2bf(f0.z); f[3] = f2bf(f0.w);
            f[4] = f2bf(f1.x); f[5] = f2bf(f1.y); f[6] = f2bf(f1.z); f[7] = f2bf(f1.w);
            afrag[a0] = __builtin_bit_cast(bf16x8, f);
        }
    }

    for (int p = 0; p < 2; p++) {
        __syncthreads();                             // LDS reuse between phases
        // stage W[:, p*128 .. +127]: coalesced float4 loads -> bf16 LDS
#pragma unroll
        for (int c = 0; c < 32; c++) {
            int f = c * 256 + tid;                   // float4 index, 0..8191
            int k = f >> 5, nc = (f & 31) * 4;
            float4 w4 = *(const float4*)&W[(size_t)k * DIM + p * 128 + nc];
            ushort4 b;
            b.x = f2bf(w4.x); b.y = f2bf(w4.y); b.z = f2bf(w4.z); b.w = f2bf(w4.w);
            *(ushort4*)&wb[k * 128 + nc] = b;
        }
        __syncthreads();

        const int ct = wave;                         // local 32-col tile, 0..3
        f32x16 acc;
#pragma unroll
        for (int i = 0; i < 16; i++) acc[i] = 0.0f;
        const int cl = ct * 32 + (lane & 31);
#pragma unroll
        for (int a0 = 0; a0 < 16; a0++) {
            const int kb = a0 * 16 + (lane >> 5) * 8;
            u16x8 f;
#pragma unroll
            for (int j = 0; j < 8; j++) f[j] = wb[(kb + j) * 128 + cl];
            acc = __builtin_amdgcn_mfma_f32_32x32x16_bf16(
                afrag[a0], __builtin_bit_cast(bf16x8, f), acc, 0, 0, 0);
        }
        const int dcol = p * 128 + ct * 32 + (lane & 31);
        const int rb0 = rt * 32 + 4 * (lane >> 5);
#pragma unroll
        for (int reg = 0; reg < 16; reg++) {
            int row = rb0 + (reg & 3) + 8 * (reg >> 2);
            dst[frag_off(row, dcol)] = f2bf(acc[reg] * scale);
        }
    }
}

// ---------------------------------------------------------------------------
// Kernels 2/3: two QK^T passes. MODE 0: row sums l_i. MODE 1: weighted column
// sums c_j. Grid 1024 = 64 rowblocks(128 rows) x 16 colchunks(512 cols).
// 2 independent MFMA chains per wave; exp epilogue deferred one step.
// ---------------------------------------------------------------------------
template <int MODE>
__global__ __launch_bounds__(256, 3) void pass_kernel(
        const uint16_t* __restrict__ qf, const uint16_t* __restrict__ kf,
        float* __restrict__ l_arr, float* __restrict__ c_arr) {
    __shared__ alignas(16) uint16_t ktile[2][8192];   // 2 x 16 KB double buffer
    __shared__ float c_lds[512];
    const int tid = threadIdx.x, lane = tid & 63, wave = tid >> 6;
    const int bid = blockIdx.x;
    const int cc = (bid & 7) | (((bid >> 3) & 1) << 3);   // XCD-aware: 2 k-slices/XCD
    const int rb = bid >> 4;
    const int t0 = rb * 4 + wave;

    // resident q fragments: 1 rowtile x 16 k-chunks = 64 regs
    bf16x8 qreg[16];
    {
        const uint4* qp = (const uint4*)qf;
#pragma unroll
        for (int a0 = 0; a0 < 16; a0++)
            qreg[a0] = __builtin_bit_cast(bf16x8, qp[(size_t)t0 * 1024 + a0 * 64 + lane]);
    }

    float rs[16];   // MODE 0 partials
    float rr[16];   // MODE 1: 1/(N*l_i)
    if (MODE == 0) {
#pragma unroll
        for (int reg = 0; reg < 16; reg++) rs[reg] = 0.0f;
    } else {
#pragma unroll
        for (int reg = 0; reg < 16; reg++) {
            int row = rb * 128 + wave * 32 + (reg & 3) + 8 * (reg >> 2) + 4 * (lane >> 5);
            rr[reg] = 1.0f / (8192.0f * l_arr[row]);
        }
        for (int i = tid; i < 512; i += 256) c_lds[i] = 0.0f;
    }

    const char* ksrc = (const char*)(kf + (size_t)cc * 16 * 8192);

    {   // prologue: stage tile 0 -> buffer 0
        const char* s0 = ksrc + wave * 4096 + lane * 16;
        char* d0 = (char*)&ktile[0][0] + wave * 4096;
#pragma unroll
        for (int it = 0; it < 4; it++) gld16(s0 + it * 1024, d0 + it * 1024);
    }

    f32x16 ae, ao;                                    // two independent chains
#pragma unroll
    for (int i = 0; i < 16; i++) { ae[i] = 0.0f; ao[i] = 0.0f; }

    for (int step = 0; step < 16; step++) {
        __syncthreads();           // tile `step` staged; other buffer free
        if (step < 15) {           // prefetch next tile (lands during compute)
            const char* sn = ksrc + (step + 1) * 16384 + wave * 4096 + lane * 16;
            char* dn = (char*)&ktile[(step + 1) & 1][0] + wave * 4096;
#pragma unroll
            for (int it = 0; it < 4; it++) gld16(sn + it * 1024, dn + it * 1024);
        }

        if (step > 0) {            // deferred epilogue for step-1 (pure VALU,
                                   // overlaps this step's ds_read latency)
            if (MODE == 0) {
#pragma unroll
                for (int reg = 0; reg < 16; reg++) rs[reg] += __expf(ae[reg] + ao[reg]);
            } else {
                float s = 0.0f;
#pragma unroll
                for (int reg = 0; reg < 16; reg++) s += __expf(ae[reg] + ao[reg]) * rr[reg];
                s += __shfl_xor(s, 32);
                if (lane < 32) atomicAdd(&c_lds[(step - 1) * 32 + lane], s);
            }
#pragma unroll
            for (int i = 0; i < 16; i++) { ae[i] = 0.0f; ao[i] = 0.0f; }
        }

        const uint16_t* kt = &ktile[step & 1][0];
#pragma unroll
        for (int a0 = 0; a0 < 8; a0++) {
            bf16x8 b0 = __builtin_bit_cast(bf16x8,
                *(const u16x8*)&kt[(size_t)((2 * a0) * 64 + lane) * 8]);
            bf16x8 b1 = __builtin_bit_cast(bf16x8,
                *(const u16x8*)&kt[(size_t)((2 * a0 + 1) * 64 + lane) * 8]);
            ae = __builtin_amdgcn_mfma_f32_32x32x16_bf16(qreg[2 * a0], b0, ae, 0, 0, 0);
            ao = __builtin_amdgcn_mfma_f32_32x32x16_bf16(qreg[2 * a0 + 1], b1, ao, 0, 0, 0);
        }
    }

    // final epilogue (step 15)
    if (MODE == 0) {
#pragma unroll
        for (int reg = 0; reg < 16; reg++) rs[reg] += __expf(ae[reg] + ao[reg]);
#pragma unroll
        for (int reg = 0; reg < 16; reg++) {
            float v = rs[reg];
            v += __shfl_xor(v, 1);  v += __shfl_xor(v, 2);  v += __shfl_xor(v, 4);
            v += __shfl_xor(v, 8);  v += __shfl_xor(v, 16);
            if ((lane & 31) == 0) {
                int row = rb * 128 + wave * 32 + (reg & 3) + 8 * (reg >> 2) + 4 * (lane >> 5);
                atomicAdd(&l_arr[row], v);
            }
        }
    } else {
        float s = 0.0f;
#pragma unroll
        for (int reg = 0; reg < 16; reg++) s += __expf(ae[reg] + ao[reg]) * rr[reg];
        s += __shfl_xor(s, 32);
        if (lane < 32) atomicAdd(&c_lds[15 * 32 + lane], s);
        __syncthreads();
        for (int i = tid; i < 512; i += 256) atomicAdd(&c_arr[cc * 512 + i], c_lds[i]);
    }
}

// ---------------------------------------------------------------------------
// Kernel 4: x = c @ h. 128 blocks x 64 rows; coalesced h reads; 128-way
// atomic contention per output element (fp32, L2-serialized, ~µs).
// ---------------------------------------------------------------------------
__global__ __launch_bounds__(256) void finish_kernel(
        const float* __restrict__ h, const float* __restrict__ c_arr,
        float* __restrict__ out) {
    const int d = threadIdx.x;
    const int j0 = blockIdx.x * 64;
    float acc = 0.0f;
    for (int j = j0; j < j0 + 64; j++) acc += c_arr[j] * h[(size_t)j * DIM + d];
    atomicAdd(&out[d], acc);
}

// ---------------------------------------------------------------------------
extern "C" void kernel_launch(void* const* d_in, const int* in_sizes, int n_in,
                              void* d_out, int out_size, void* d_ws, size_t ws_size,
                              hipStream_t stream) {
    const float* h  = (const float*)d_in[0];
    const float* Wq = (const float*)d_in[1];
    const float* Wk = (const float*)d_in[2];

    uint16_t* qf = (uint16_t*)d_ws;
    uint16_t* kf = qf + (size_t)N_ROWS * DIM;
    float* l_arr = (float*)((char*)d_ws + (size_t)8 * 1024 * 1024);
    float* c_arr = l_arr + N_ROWS;
    float* out = (float*)d_out;

    proj_kernel<<<512, 256, 0, stream>>>(h, Wq, Wk, qf, kf, l_arr, c_arr, out);
    pass_kernel<0><<<1024, 256, 0, stream>>>(qf, kf, l_arr, c_arr);
    pass_kernel<1><<<1024, 256, 0, stream>>>(qf, kf, l_arr, c_arr);
    finish_kernel<<<128, 256, 0, stream>>>(h, c_arr, out);
}